// Round 5
// baseline (713.752 us; speedup 1.0000x reference)
//
#include <hip/hip_runtime.h>

#define NNODES 100000
#define FDIM 128
#define NLAYERS 5

typedef __bf16 bf16_t;
typedef bf16_t bf16x8 __attribute__((ext_vector_type(8)));
typedef float  f32x4  __attribute__((ext_vector_type(4)));

__device__ __forceinline__ bf16_t f2bf(float f){ return (bf16_t)f; }
__device__ __forceinline__ float bfbits_lo(unsigned u){
  unsigned b = u << 16; return __builtin_bit_cast(float, b);
}
__device__ __forceinline__ float bfbits_hi(unsigned u){
  unsigned b = u & 0xffff0000u; return __builtin_bit_cast(float, b);
}
__device__ __forceinline__ unsigned short bfb(float f){
  bf16_t b = (bf16_t)f; return __builtin_bit_cast(unsigned short, b);
}
__device__ __forceinline__ float us2f(unsigned short u){
  unsigned b = ((unsigned)u) << 16; return __builtin_bit_cast(float, b);
}

// ---------------- CSR build ----------------
__global__ void deg_kernel(const int* __restrict__ dstv, int* __restrict__ deg, int E){
  int e = blockIdx.x*256 + threadIdx.x;
  if(e < E) atomicAdd(&deg[dstv[e]], 1);
}

__global__ void scan1_kernel(const int* __restrict__ deg, int* __restrict__ row_start,
                             int* __restrict__ sums, int n){
  __shared__ int sm[256];
  int t = threadIdx.x;
  int base = blockIdx.x*1024 + t*4;
  int v0=0,v1=0,v2=0,v3=0;
  if(base+3 < n){ int4 q = *(const int4*)(deg+base); v0=q.x; v1=q.y; v2=q.z; v3=q.w; }
  else {
    if(base   < n) v0 = deg[base];
    if(base+1 < n) v1 = deg[base+1];
    if(base+2 < n) v2 = deg[base+2];
    if(base+3 < n) v3 = deg[base+3];
  }
  int s = v0+v1+v2+v3;
  sm[t] = s;
  __syncthreads();
  for(int off=1; off<256; off<<=1){
    int y = (t>=off) ? sm[t-off] : 0;
    __syncthreads();
    sm[t] += y;
    __syncthreads();
  }
  int excl = sm[t] - s;
  if(base   < n) row_start[base]   = excl;
  if(base+1 < n) row_start[base+1] = excl+v0;
  if(base+2 < n) row_start[base+2] = excl+v0+v1;
  if(base+3 < n) row_start[base+3] = excl+v0+v1+v2;
  if(t == 255) sums[blockIdx.x] = sm[255];
}

__global__ void scan2_kernel(int* sums, int nc){
  __shared__ int sm[128];
  int t = threadIdx.x;
  int v = (t<nc) ? sums[t] : 0;
  sm[t] = v;
  __syncthreads();
  for(int off=1; off<128; off<<=1){
    int y = (t>=off) ? sm[t-off] : 0;
    __syncthreads();
    sm[t] += y;
    __syncthreads();
  }
  if(t<nc) sums[t] = sm[t] - v;
}

__global__ void scan3_kernel(int* row_start, const int* __restrict__ sums, int n, int E){
  int i = blockIdx.x*256 + threadIdx.x;
  if(i < n)       row_start[i] += sums[i>>10];
  else if(i == n) row_start[n]  = E;
}

__global__ void fill_kernel(const int* __restrict__ srcv, const int* __restrict__ dstv,
                            const int* __restrict__ row_start, int* __restrict__ cnt,
                            int* __restrict__ csr, int E){
  int e = blockIdx.x*256 + threadIdx.x;
  if(e < E){
    int d = dstv[e];
    int p = atomicAdd(&cnt[d], 1);
    csr[row_start[d] + p] = srcv[e];
  }
}

// ---------------- x fp32 -> bf16 pre-convert ----------------
__global__ __launch_bounds__(256) void cvt_kernel(const float* __restrict__ x,
                                                  unsigned short* __restrict__ xb){
  long i = ((long)blockIdx.x*256 + threadIdx.x)*8;
  float4 q0 = *(const float4*)(x+i);
  float4 q1 = *(const float4*)(x+i+4);
  unsigned short o[8];
  o[0]=bfb(q0.x); o[1]=bfb(q0.y); o[2]=bfb(q0.z); o[3]=bfb(q0.w);
  o[4]=bfb(q1.x); o[5]=bfb(q1.y); o[6]=bfb(q1.z); o[7]=bfb(q1.w);
  *(ulong2*)(xb+i) = *(ulong2*)o;
}

// ---------------- per-node gather, unroll-4 ----------------
__global__ __launch_bounds__(256) void gather_kernel(const unsigned short* __restrict__ xb,
                                                     const int* __restrict__ row_start,
                                                     const int* __restrict__ csr,
                                                     unsigned short* __restrict__ agg, int n){
  int wid  = (blockIdx.x*256 + threadIdx.x) >> 6;
  int lane = threadIdx.x & 63;
  if(wid >= n) return;
  int s0 = row_start[wid];
  int s1 = row_start[wid+1];
  float ax0=0.f, ay0=0.f, ax1=0.f, ay1=0.f;
  float ax2=0.f, ay2=0.f, ax3=0.f, ay3=0.f;
  int i = s0;
  for(; i+4 <= s1; i += 4){
    int c0 = csr[i], c1 = csr[i+1], c2 = csr[i+2], c3 = csr[i+3];
    unsigned v0 = *(const unsigned*)(xb + (size_t)c0*FDIM + lane*2);
    unsigned v1 = *(const unsigned*)(xb + (size_t)c1*FDIM + lane*2);
    unsigned v2 = *(const unsigned*)(xb + (size_t)c2*FDIM + lane*2);
    unsigned v3 = *(const unsigned*)(xb + (size_t)c3*FDIM + lane*2);
    ax0 += bfbits_lo(v0); ay0 += bfbits_hi(v0);
    ax1 += bfbits_lo(v1); ay1 += bfbits_hi(v1);
    ax2 += bfbits_lo(v2); ay2 += bfbits_hi(v2);
    ax3 += bfbits_lo(v3); ay3 += bfbits_hi(v3);
  }
  if(i+2 <= s1){
    int c0 = csr[i], c1 = csr[i+1];
    unsigned v0 = *(const unsigned*)(xb + (size_t)c0*FDIM + lane*2);
    unsigned v1 = *(const unsigned*)(xb + (size_t)c1*FDIM + lane*2);
    ax0 += bfbits_lo(v0); ay0 += bfbits_hi(v0);
    ax1 += bfbits_lo(v1); ay1 += bfbits_hi(v1);
    i += 2;
  }
  if(i < s1){
    int c0 = csr[i];
    unsigned v0 = *(const unsigned*)(xb + (size_t)c0*FDIM + lane*2);
    ax2 += bfbits_lo(v0); ay2 += bfbits_hi(v0);
  }
  float ax = (ax0+ax1)+(ax2+ax3), ay = (ay0+ay1)+(ay2+ay3);
  unsigned o = (unsigned)bfb(ax) | ((unsigned)bfb(ay) << 16);
  *(unsigned*)(agg + (size_t)wid*FDIM + lane*2) = o;
}

// ---------------- weight prepack: Wc=[Wr;Wroot] -> bf16 MFMA fragments ----------------
__global__ void wprep_kernel(const float* __restrict__ Wrel, const float* __restrict__ Wroot,
                             bf16_t* __restrict__ Bp){
  int gid = blockIdx.x*256 + threadIdx.x;
  if(gid >= NLAYERS*64*64) return;
  int lane = gid & 63;
  int fg   = (gid>>6) & 63;
  int l    = gid >> 12;
  int kk = fg >> 3, cb = fg & 7;
  int kbase = kk*32 + (lane>>4)*8;
  int col   = cb*16 + (lane&15);
  bf16_t tmp[8];
  #pragma unroll
  for(int e=0;e<8;e++){
    int k = kbase + e;
    float v = (k < FDIM) ? Wrel [l*FDIM*FDIM + k*FDIM + col]
                         : Wroot[l*FDIM*FDIM + (k-FDIM)*FDIM + col];
    tmp[e] = f2bf(v);
  }
  bf16_t* o = Bp + (long)gid*8;
  #pragma unroll
  for(int e=0;e<8;e++) o[e] = tmp[e];
}

// ---------------- fused GEMM: out = epi(agg@Wr + x@Wroot + b) ----------------
// B staged in LDS (64 KiB -> 2 blocks/CU = 16 waves/CU). Live state kept
// minimal so the (512,2) 128-VGPR cap holds with NO scratch spill:
//   - A fragment loaded inside kk loop (one bf16x8 live at a time)
//   - bias loaded in the epilogue, not hoisted
__global__ __launch_bounds__(512, 2) void gemm_kernel(
    const bf16_t* __restrict__ Aagg, const bf16_t* __restrict__ Ain,
    const bf16_t* __restrict__ Bp, const float* __restrict__ bias,
    bf16_t* __restrict__ outB, float* __restrict__ outF,
    int relu, int resf, int ntiles, int nwaves){
  __shared__ char Bs[65536];
  int tid = threadIdx.x;
  {
    const char* g = (const char*)Bp;
    #pragma unroll
    for(int j=0;j<8;j++){
      int off = tid*16 + j*8192;
      *(ulong2*)(Bs+off) = *(const ulong2*)(g+off);
    }
  }
  __syncthreads();
  int lane = tid & 63;
  int wave = tid >> 6;
  int gw   = blockIdx.x*8 + wave;
  int r_lo = lane & 15;
  int kgrp = lane >> 4;

  for(int t = gw; t < ntiles; t += nwaves){
    long r0 = (long)t*16;
    const bf16_t* pa = Aagg + (r0 + r_lo)*FDIM + kgrp*8;
    const bf16_t* pi = Ain  + (r0 + r_lo)*FDIM + kgrp*8;
    f32x4 acc[8] = {};
    #pragma unroll
    for(int kk=0;kk<8;kk++){
      bf16x8 a = (kk<4) ? *(const bf16x8*)(pa + kk*32)
                        : *(const bf16x8*)(pi + (kk-4)*32);
      #pragma unroll
      for(int cb=0;cb<8;cb++){
        bf16x8 wfr = *(const bf16x8*)(Bs + (((kk<<3)|cb)*64 + lane)*16);
        acc[cb] = __builtin_amdgcn_mfma_f32_16x16x32_bf16(wfr, a, acc[cb], 0, 0, 0);
      }
    }
    // epilogue: lane owns node row (r0 + r_lo), cols cb*16 + kgrp*4 .. +3
    long nrow = r0 + r_lo;
    #pragma unroll
    for(int cb=0;cb<8;cb++){
      int col = cb*16 + kgrp*4;
      float4 bv = *(const float4*)(bias + col);
      float v0 = acc[cb][0] + bv.x;
      float v1 = acc[cb][1] + bv.y;
      float v2 = acc[cb][2] + bv.z;
      float v3 = acc[cb][3] + bv.w;
      if(relu){ v0=fmaxf(v0,0.f); v1=fmaxf(v1,0.f); v2=fmaxf(v2,0.f); v3=fmaxf(v3,0.f); }
      if(resf){
        ushort4 rv = *(const ushort4*)((const unsigned short*)Ain + nrow*FDIM + col);
        v0 += us2f(rv.x); v1 += us2f(rv.y); v2 += us2f(rv.z); v3 += us2f(rv.w);
      }
      if(outF){
        float4 o; o.x=v0; o.y=v1; o.z=v2; o.w=v3;
        *(float4*)(outF + nrow*FDIM + col) = o;
      } else {
        uint2 o;
        o.x = (unsigned)bfb(v0) | ((unsigned)bfb(v1) << 16);
        o.y = (unsigned)bfb(v2) | ((unsigned)bfb(v3) << 16);
        *(uint2*)((unsigned short*)outB + nrow*FDIM + col) = o;
      }
    }
  }
}

extern "C" void kernel_launch(void* const* d_in, const int* in_sizes, int n_in,
                              void* d_out, int out_size, void* d_ws, size_t ws_size,
                              hipStream_t stream){
  const float* x     = (const float*)d_in[0];
  const int*   ei    = (const int*)  d_in[1];
  const float* Wrel  = (const float*)d_in[2];
  const float* brel  = (const float*)d_in[3];
  const float* Wroot = (const float*)d_in[4];
  float* out = (float*)d_out;

  const int N = NNODES;
  const int E = in_sizes[1] / 2;
  const int* srcv = ei;
  const int* dstv = ei + E;

  char* w = (char*)d_ws;
  auto alloc = [&](size_t b)->char*{ char* p = w; w += (b + 255) & ~(size_t)255; return p; };
  unsigned short* xb  = (unsigned short*)alloc((size_t)N*FDIM*2);
  unsigned short* h_a = (unsigned short*)alloc((size_t)N*FDIM*2);
  unsigned short* h_b = (unsigned short*)alloc((size_t)N*FDIM*2);
  unsigned short* agg = (unsigned short*)alloc((size_t)N*FDIM*2);
  int*    deg       = (int*)   alloc((size_t)N*4);
  int*    cnt       = (int*)   alloc((size_t)N*4);
  int*    row_start = (int*)   alloc((size_t)(N+1)*4);
  int*    csr       = (int*)   alloc((size_t)E*4);
  bf16_t* Bp        = (bf16_t*)alloc((size_t)NLAYERS*4096*8*2);
  int*    sums      = (int*)   alloc(512);

  hipMemsetAsync(deg, 0, (size_t)N*4, stream);
  hipMemsetAsync(cnt, 0, (size_t)N*4, stream);

  int eb = (E + 255) / 256;
  int nchunks = (N + 1023) / 1024;
  deg_kernel <<<eb, 256, 0, stream>>>(dstv, deg, E);
  scan1_kernel<<<nchunks, 256, 0, stream>>>(deg, row_start, sums, N);
  scan2_kernel<<<1, 128, 0, stream>>>(sums, nchunks);
  scan3_kernel<<<(N + 1 + 255)/256, 256, 0, stream>>>(row_start, sums, N, E);
  fill_kernel<<<eb, 256, 0, stream>>>(srcv, dstv, row_start, cnt, csr, E);
  wprep_kernel<<<(NLAYERS*4096 + 255)/256, 256, 0, stream>>>(Wrel, Wroot, Bp);
  cvt_kernel  <<<(N*FDIM/8 + 255)/256, 256, 0, stream>>>(x, xb);

  const int ntiles  = N / 16;       // 6250
  const int gblocks = 782;          // 6256 waves -> 1 tile/wave
  const int nwaves  = gblocks * 8;

  typedef unsigned short us;
  struct Lay { const us* in; us* o; int relu; int res; };
  Lay L[5] = {
    { xb,  h_a, 1, 0 },
    { h_a, h_b, 1, 1 },
    { h_b, h_a, 1, 1 },
    { h_a, h_b, 1, 1 },
    { h_b, 0,   0, 1 },
  };
  for(int l=0; l<NLAYERS; l++){
    gather_kernel<<<N/4, 256, 0, stream>>>(L[l].in, row_start, csr, agg, N);
    gemm_kernel  <<<gblocks, 512, 0, stream>>>((const bf16_t*)agg, (const bf16_t*)L[l].in,
                                               Bp + (size_t)l*4096*8,
                                               brel + l*FDIM,
                                               (bf16_t*)L[l].o, (l==4)? out : nullptr,
                                               L[l].relu, L[l].res,
                                               ntiles, nwaves);
  }
}

// Round 6
// 453.763 us; speedup vs baseline: 1.5730x; 1.5730x over previous
//
#include <hip/hip_runtime.h>

#define NNODES 100000
#define FDIM 128
#define NLAYERS 5

typedef __bf16 bf16_t;
typedef bf16_t bf16x8 __attribute__((ext_vector_type(8)));
typedef float  f32x4  __attribute__((ext_vector_type(4)));

__device__ __forceinline__ bf16_t f2bf(float f){ return (bf16_t)f; }
__device__ __forceinline__ float bfbits_lo(unsigned u){
  unsigned b = u << 16; return __builtin_bit_cast(float, b);
}
__device__ __forceinline__ float bfbits_hi(unsigned u){
  unsigned b = u & 0xffff0000u; return __builtin_bit_cast(float, b);
}
__device__ __forceinline__ unsigned short bfb(float f){
  bf16_t b = (bf16_t)f; return __builtin_bit_cast(unsigned short, b);
}
__device__ __forceinline__ float us2f(unsigned short u){
  unsigned b = ((unsigned)u) << 16; return __builtin_bit_cast(float, b);
}

// ---------------- CSR build ----------------
__global__ void deg_kernel(const int* __restrict__ dstv, int* __restrict__ deg, int E){
  int e = blockIdx.x*256 + threadIdx.x;
  if(e < E) atomicAdd(&deg[dstv[e]], 1);
}

__global__ void scan1_kernel(const int* __restrict__ deg, int* __restrict__ row_start,
                             int* __restrict__ sums, int n){
  __shared__ int sm[256];
  int t = threadIdx.x;
  int base = blockIdx.x*1024 + t*4;
  int v0=0,v1=0,v2=0,v3=0;
  if(base+3 < n){ int4 q = *(const int4*)(deg+base); v0=q.x; v1=q.y; v2=q.z; v3=q.w; }
  else {
    if(base   < n) v0 = deg[base];
    if(base+1 < n) v1 = deg[base+1];
    if(base+2 < n) v2 = deg[base+2];
    if(base+3 < n) v3 = deg[base+3];
  }
  int s = v0+v1+v2+v3;
  sm[t] = s;
  __syncthreads();
  for(int off=1; off<256; off<<=1){
    int y = (t>=off) ? sm[t-off] : 0;
    __syncthreads();
    sm[t] += y;
    __syncthreads();
  }
  int excl = sm[t] - s;
  if(base   < n) row_start[base]   = excl;
  if(base+1 < n) row_start[base+1] = excl+v0;
  if(base+2 < n) row_start[base+2] = excl+v0+v1;
  if(base+3 < n) row_start[base+3] = excl+v0+v1+v2;
  if(t == 255) sums[blockIdx.x] = sm[255];
}

__global__ void scan2_kernel(int* sums, int nc){
  __shared__ int sm[128];
  int t = threadIdx.x;
  int v = (t<nc) ? sums[t] : 0;
  sm[t] = v;
  __syncthreads();
  for(int off=1; off<128; off<<=1){
    int y = (t>=off) ? sm[t-off] : 0;
    __syncthreads();
    sm[t] += y;
    __syncthreads();
  }
  if(t<nc) sums[t] = sm[t] - v;
}

__global__ void scan3_kernel(int* row_start, const int* __restrict__ sums, int n, int E){
  int i = blockIdx.x*256 + threadIdx.x;
  if(i < n)       row_start[i] += sums[i>>10];
  else if(i == n) row_start[n]  = E;
}

__global__ void fill_kernel(const int* __restrict__ srcv, const int* __restrict__ dstv,
                            const int* __restrict__ row_start, int* __restrict__ cnt,
                            int* __restrict__ csr, int E){
  int e = blockIdx.x*256 + threadIdx.x;
  if(e < E){
    int d = dstv[e];
    int p = atomicAdd(&cnt[d], 1);
    csr[row_start[d] + p] = srcv[e];
  }
}

// ---------------- x fp32 -> bf16 pre-convert ----------------
__global__ __launch_bounds__(256) void cvt_kernel(const float* __restrict__ x,
                                                  unsigned short* __restrict__ xb){
  long i = ((long)blockIdx.x*256 + threadIdx.x)*8;
  float4 q0 = *(const float4*)(x+i);
  float4 q1 = *(const float4*)(x+i+4);
  unsigned short o[8];
  o[0]=bfb(q0.x); o[1]=bfb(q0.y); o[2]=bfb(q0.z); o[3]=bfb(q0.w);
  o[4]=bfb(q1.x); o[5]=bfb(q1.y); o[6]=bfb(q1.z); o[7]=bfb(q1.w);
  *(ulong2*)(xb+i) = *(ulong2*)o;
}

// ---------------- per-node gather, unroll-4 ----------------
__global__ __launch_bounds__(256) void gather_kernel(const unsigned short* __restrict__ xb,
                                                     const int* __restrict__ row_start,
                                                     const int* __restrict__ csr,
                                                     unsigned short* __restrict__ agg, int n){
  int wid  = (blockIdx.x*256 + threadIdx.x) >> 6;
  int lane = threadIdx.x & 63;
  if(wid >= n) return;
  int s0 = row_start[wid];
  int s1 = row_start[wid+1];
  float ax0=0.f, ay0=0.f, ax1=0.f, ay1=0.f;
  float ax2=0.f, ay2=0.f, ax3=0.f, ay3=0.f;
  int i = s0;
  for(; i+4 <= s1; i += 4){
    int c0 = csr[i], c1 = csr[i+1], c2 = csr[i+2], c3 = csr[i+3];
    unsigned v0 = *(const unsigned*)(xb + (size_t)c0*FDIM + lane*2);
    unsigned v1 = *(const unsigned*)(xb + (size_t)c1*FDIM + lane*2);
    unsigned v2 = *(const unsigned*)(xb + (size_t)c2*FDIM + lane*2);
    unsigned v3 = *(const unsigned*)(xb + (size_t)c3*FDIM + lane*2);
    ax0 += bfbits_lo(v0); ay0 += bfbits_hi(v0);
    ax1 += bfbits_lo(v1); ay1 += bfbits_hi(v1);
    ax2 += bfbits_lo(v2); ay2 += bfbits_hi(v2);
    ax3 += bfbits_lo(v3); ay3 += bfbits_hi(v3);
  }
  if(i+2 <= s1){
    int c0 = csr[i], c1 = csr[i+1];
    unsigned v0 = *(const unsigned*)(xb + (size_t)c0*FDIM + lane*2);
    unsigned v1 = *(const unsigned*)(xb + (size_t)c1*FDIM + lane*2);
    ax0 += bfbits_lo(v0); ay0 += bfbits_hi(v0);
    ax1 += bfbits_lo(v1); ay1 += bfbits_hi(v1);
    i += 2;
  }
  if(i < s1){
    int c0 = csr[i];
    unsigned v0 = *(const unsigned*)(xb + (size_t)c0*FDIM + lane*2);
    ax2 += bfbits_lo(v0); ay2 += bfbits_hi(v0);
  }
  float ax = (ax0+ax1)+(ax2+ax3), ay = (ay0+ay1)+(ay2+ay3);
  unsigned o = (unsigned)bfb(ax) | ((unsigned)bfb(ay) << 16);
  *(unsigned*)(agg + (size_t)wid*FDIM + lane*2) = o;
}

// ---------------- weight prepack: Wc=[Wr;Wroot] -> bf16 MFMA fragments ----------------
// frag (kk,cb): holds Wc[k = kk*32 + (lane>>4)*8 + e][col = cb*16 + (lane&15)]
__global__ void wprep_kernel(const float* __restrict__ Wrel, const float* __restrict__ Wroot,
                             bf16_t* __restrict__ Bp){
  int gid = blockIdx.x*256 + threadIdx.x;
  if(gid >= NLAYERS*64*64) return;
  int lane = gid & 63;
  int fg   = (gid>>6) & 63;
  int l    = gid >> 12;
  int kk = fg >> 3, cb = fg & 7;
  int kbase = kk*32 + (lane>>4)*8;
  int col   = cb*16 + (lane&15);
  bf16_t tmp[8];
  #pragma unroll
  for(int e=0;e<8;e++){
    int k = kbase + e;
    float v = (k < FDIM) ? Wrel [l*FDIM*FDIM + k*FDIM + col]
                         : Wroot[l*FDIM*FDIM + (k-FDIM)*FDIM + col];
    tmp[e] = f2bf(v);
  }
  bf16_t* o = Bp + (long)gid*8;
  #pragma unroll
  for(int e=0;e<8;e++) o[e] = tmp[e];
}

// ---------------- fused GEMM: out = epi(agg@Wr + x@Wroot + b) ----------------
// NO LDS (R3-R5 LDS variants all induced scratch pathology; R2 global-B was
// traffic-clean). Each wave owns TWO 16-row tiles (32 contiguous rows): every
// B-fragment load from L2 feeds 2 MFMAs -> half the B traffic, double the ILP.
// W-fragments as MFMA operand A -> D[node_row = lane&15][wcol=(lane>>4)*4+r],
// lane owns 4 consecutive output cols per cb block.
__global__ __launch_bounds__(256) void gemm_kernel(
    const bf16_t* __restrict__ Aagg, const bf16_t* __restrict__ Ain,
    const bf16_t* __restrict__ Bp, const float* __restrict__ bias,
    bf16_t* __restrict__ outB, float* __restrict__ outF,
    int relu, int resf, int npairs){
  int lane = threadIdx.x & 63;
  int gw   = (blockIdx.x*256 + threadIdx.x) >> 6;   // one 32-row pair per wave
  if(gw >= npairs) return;
  int r_lo = lane & 15;
  int kgrp = lane >> 4;
  long r0 = (long)gw*32;

  const bf16_t* pa0 = Aagg + (r0      + r_lo)*FDIM + kgrp*8;
  const bf16_t* pa1 = Aagg + (r0 + 16 + r_lo)*FDIM + kgrp*8;
  const bf16_t* pi0 = Ain  + (r0      + r_lo)*FDIM + kgrp*8;
  const bf16_t* pi1 = Ain  + (r0 + 16 + r_lo)*FDIM + kgrp*8;

  f32x4 acc0[8] = {};
  f32x4 acc1[8] = {};
  #pragma unroll
  for(int kk=0;kk<8;kk++){
    bf16x8 a0 = (kk<4) ? *(const bf16x8*)(pa0 + kk*32) : *(const bf16x8*)(pi0 + (kk-4)*32);
    bf16x8 a1 = (kk<4) ? *(const bf16x8*)(pa1 + kk*32) : *(const bf16x8*)(pi1 + (kk-4)*32);
    #pragma unroll
    for(int cb=0;cb<8;cb++){
      bf16x8 wfr = *(const bf16x8*)(Bp + (((kk<<3)|cb)*64 + lane)*8);
      acc0[cb] = __builtin_amdgcn_mfma_f32_16x16x32_bf16(wfr, a0, acc0[cb], 0, 0, 0);
      acc1[cb] = __builtin_amdgcn_mfma_f32_16x16x32_bf16(wfr, a1, acc1[cb], 0, 0, 0);
    }
  }
  // epilogue: two rows per lane: r0+r_lo and r0+16+r_lo; cols cb*16+kgrp*4..+3
  #pragma unroll
  for(int half=0; half<2; half++){
    long nrow = r0 + half*16 + r_lo;
    f32x4* acc = half ? acc1 : acc0;
    #pragma unroll
    for(int cb=0;cb<8;cb++){
      int col = cb*16 + kgrp*4;
      float4 bv = *(const float4*)(bias + col);
      float v0 = acc[cb][0] + bv.x;
      float v1 = acc[cb][1] + bv.y;
      float v2 = acc[cb][2] + bv.z;
      float v3 = acc[cb][3] + bv.w;
      if(relu){ v0=fmaxf(v0,0.f); v1=fmaxf(v1,0.f); v2=fmaxf(v2,0.f); v3=fmaxf(v3,0.f); }
      if(resf){
        ushort4 rv = *(const ushort4*)((const unsigned short*)Ain + nrow*FDIM + col);
        v0 += us2f(rv.x); v1 += us2f(rv.y); v2 += us2f(rv.z); v3 += us2f(rv.w);
      }
      if(outF){
        float4 o; o.x=v0; o.y=v1; o.z=v2; o.w=v3;
        *(float4*)(outF + nrow*FDIM + col) = o;
      } else {
        uint2 o;
        o.x = (unsigned)bfb(v0) | ((unsigned)bfb(v1) << 16);
        o.y = (unsigned)bfb(v2) | ((unsigned)bfb(v3) << 16);
        *(uint2*)((unsigned short*)outB + nrow*FDIM + col) = o;
      }
    }
  }
}

extern "C" void kernel_launch(void* const* d_in, const int* in_sizes, int n_in,
                              void* d_out, int out_size, void* d_ws, size_t ws_size,
                              hipStream_t stream){
  const float* x     = (const float*)d_in[0];
  const int*   ei    = (const int*)  d_in[1];
  const float* Wrel  = (const float*)d_in[2];
  const float* brel  = (const float*)d_in[3];
  const float* Wroot = (const float*)d_in[4];
  float* out = (float*)d_out;

  const int N = NNODES;
  const int E = in_sizes[1] / 2;
  const int* srcv = ei;
  const int* dstv = ei + E;

  char* w = (char*)d_ws;
  auto alloc = [&](size_t b)->char*{ char* p = w; w += (b + 255) & ~(size_t)255; return p; };
  unsigned short* xb  = (unsigned short*)alloc((size_t)N*FDIM*2);
  unsigned short* h_a = (unsigned short*)alloc((size_t)N*FDIM*2);
  unsigned short* h_b = (unsigned short*)alloc((size_t)N*FDIM*2);
  unsigned short* agg = (unsigned short*)alloc((size_t)N*FDIM*2);
  int*    deg       = (int*)   alloc((size_t)N*4);
  int*    cnt       = (int*)   alloc((size_t)N*4);
  int*    row_start = (int*)   alloc((size_t)(N+1)*4);
  int*    csr       = (int*)   alloc((size_t)E*4);
  bf16_t* Bp        = (bf16_t*)alloc((size_t)NLAYERS*4096*8*2);
  int*    sums      = (int*)   alloc(512);

  hipMemsetAsync(deg, 0, (size_t)N*4, stream);
  hipMemsetAsync(cnt, 0, (size_t)N*4, stream);

  int eb = (E + 255) / 256;
  int nchunks = (N + 1023) / 1024;
  deg_kernel <<<eb, 256, 0, stream>>>(dstv, deg, E);
  scan1_kernel<<<nchunks, 256, 0, stream>>>(deg, row_start, sums, N);
  scan2_kernel<<<1, 128, 0, stream>>>(sums, nchunks);
  scan3_kernel<<<(N + 1 + 255)/256, 256, 0, stream>>>(row_start, sums, N, E);
  fill_kernel<<<eb, 256, 0, stream>>>(srcv, dstv, row_start, cnt, csr, E);
  wprep_kernel<<<(NLAYERS*4096 + 255)/256, 256, 0, stream>>>(Wrel, Wroot, Bp);
  cvt_kernel  <<<(N*FDIM/8 + 255)/256, 256, 0, stream>>>(x, xb);

  const int npairs  = N / 32;                 // 3125 wave-pairs, exact
  const int gblocks = (npairs + 3) / 4;       // 4 waves/block of 256 thr -> 782

  typedef unsigned short us;
  struct Lay { const us* in; us* o; int relu; int res; };
  Lay L[5] = {
    { xb,  h_a, 1, 0 },
    { h_a, h_b, 1, 1 },
    { h_b, h_a, 1, 1 },
    { h_a, h_b, 1, 1 },
    { h_b, 0,   0, 1 },
  };
  for(int l=0; l<NLAYERS; l++){
    gather_kernel<<<N/4, 256, 0, stream>>>(L[l].in, row_start, csr, agg, N);
    gemm_kernel  <<<gblocks, 256, 0, stream>>>((const bf16_t*)agg, (const bf16_t*)L[l].in,
                                               Bp + (size_t)l*4096*8,
                                               brel + l*FDIM,
                                               (bf16_t*)L[l].o, (l==4)? out : nullptr,
                                               L[l].relu, L[l].res, npairs);
  }
}

// Round 7
// 447.338 us; speedup vs baseline: 1.5956x; 1.0144x over previous
//
#include <hip/hip_runtime.h>

#define NNODES 100000
#define FDIM 128
#define NLAYERS 5

typedef __bf16 bf16_t;
typedef bf16_t bf16x8 __attribute__((ext_vector_type(8)));
typedef float  f32x4  __attribute__((ext_vector_type(4)));

__device__ __forceinline__ bf16_t f2bf(float f){ return (bf16_t)f; }
__device__ __forceinline__ float bfbits_lo(unsigned u){
  unsigned b = u << 16; return __builtin_bit_cast(float, b);
}
__device__ __forceinline__ float bfbits_hi(unsigned u){
  unsigned b = u & 0xffff0000u; return __builtin_bit_cast(float, b);
}
__device__ __forceinline__ unsigned short bfb(float f){
  bf16_t b = (bf16_t)f; return __builtin_bit_cast(unsigned short, b);
}
__device__ __forceinline__ float us2f(unsigned short u){
  unsigned b = ((unsigned)u) << 16; return __builtin_bit_cast(float, b);
}

// ---------------- CSR build ----------------
__global__ void deg_kernel(const int* __restrict__ dstv, int* __restrict__ deg, int E){
  int e = blockIdx.x*256 + threadIdx.x;
  if(e < E) atomicAdd(&deg[dstv[e]], 1);
}

__global__ void scan1_kernel(const int* __restrict__ deg, int* __restrict__ row_start,
                             int* __restrict__ sums, int n){
  __shared__ int sm[256];
  int t = threadIdx.x;
  int base = blockIdx.x*1024 + t*4;
  int v0=0,v1=0,v2=0,v3=0;
  if(base+3 < n){ int4 q = *(const int4*)(deg+base); v0=q.x; v1=q.y; v2=q.z; v3=q.w; }
  else {
    if(base   < n) v0 = deg[base];
    if(base+1 < n) v1 = deg[base+1];
    if(base+2 < n) v2 = deg[base+2];
    if(base+3 < n) v3 = deg[base+3];
  }
  int s = v0+v1+v2+v3;
  sm[t] = s;
  __syncthreads();
  for(int off=1; off<256; off<<=1){
    int y = (t>=off) ? sm[t-off] : 0;
    __syncthreads();
    sm[t] += y;
    __syncthreads();
  }
  int excl = sm[t] - s;
  if(base   < n) row_start[base]   = excl;
  if(base+1 < n) row_start[base+1] = excl+v0;
  if(base+2 < n) row_start[base+2] = excl+v0+v1;
  if(base+3 < n) row_start[base+3] = excl+v0+v1+v2;
  if(t == 255) sums[blockIdx.x] = sm[255];
}

__global__ void scan2_kernel(int* sums, int nc){
  __shared__ int sm[128];
  int t = threadIdx.x;
  int v = (t<nc) ? sums[t] : 0;
  sm[t] = v;
  __syncthreads();
  for(int off=1; off<128; off<<=1){
    int y = (t>=off) ? sm[t-off] : 0;
    __syncthreads();
    sm[t] += y;
    __syncthreads();
  }
  if(t<nc) sums[t] = sm[t] - v;
}

__global__ void scan3_kernel(int* row_start, const int* __restrict__ sums, int n, int E){
  int i = blockIdx.x*256 + threadIdx.x;
  if(i < n)       row_start[i] += sums[i>>10];
  else if(i == n) row_start[n]  = E;
}

__global__ void fill_kernel(const int* __restrict__ srcv, const int* __restrict__ dstv,
                            const int* __restrict__ row_start, int* __restrict__ cnt,
                            int* __restrict__ csr, int E){
  int e = blockIdx.x*256 + threadIdx.x;
  if(e < E){
    int d = dstv[e];
    int p = atomicAdd(&cnt[d], 1);
    csr[row_start[d] + p] = srcv[e];
  }
}

// ---------------- x fp32 -> bf16 pre-convert ----------------
__global__ __launch_bounds__(256) void cvt_kernel(const float* __restrict__ x,
                                                  unsigned short* __restrict__ xb){
  long i = ((long)blockIdx.x*256 + threadIdx.x)*8;
  float4 q0 = *(const float4*)(x+i);
  float4 q1 = *(const float4*)(x+i+4);
  unsigned short o[8];
  o[0]=bfb(q0.x); o[1]=bfb(q0.y); o[2]=bfb(q0.z); o[3]=bfb(q0.w);
  o[4]=bfb(q1.x); o[5]=bfb(q1.y); o[6]=bfb(q1.z); o[7]=bfb(q1.w);
  *(ulong2*)(xb+i) = *(ulong2*)o;
}

// ---------------- per-node gather, 8 loads in flight ----------------
__global__ __launch_bounds__(256) void gather_kernel(const unsigned short* __restrict__ xb,
                                                     const int* __restrict__ row_start,
                                                     const int* __restrict__ csr,
                                                     unsigned short* __restrict__ agg, int n){
  int wid  = (blockIdx.x*256 + threadIdx.x) >> 6;
  int lane = threadIdx.x & 63;
  if(wid >= n) return;
  int s0 = row_start[wid];
  int s1 = row_start[wid+1];
  float ax[8] = {}, ay[8] = {};
  int i = s0;
  for(; i+8 <= s1; i += 8){
    unsigned v[8];
    #pragma unroll
    for(int j=0;j<8;j++){
      int c = csr[i+j];
      v[j] = *(const unsigned*)(xb + (size_t)c*FDIM + lane*2);
    }
    #pragma unroll
    for(int j=0;j<8;j++){ ax[j] += bfbits_lo(v[j]); ay[j] += bfbits_hi(v[j]); }
  }
  if(i+4 <= s1){
    unsigned v[4];
    #pragma unroll
    for(int j=0;j<4;j++){
      int c = csr[i+j];
      v[j] = *(const unsigned*)(xb + (size_t)c*FDIM + lane*2);
    }
    #pragma unroll
    for(int j=0;j<4;j++){ ax[j] += bfbits_lo(v[j]); ay[j] += bfbits_hi(v[j]); }
    i += 4;
  }
  if(i+2 <= s1){
    unsigned v0 = *(const unsigned*)(xb + (size_t)csr[i]*FDIM + lane*2);
    unsigned v1 = *(const unsigned*)(xb + (size_t)csr[i+1]*FDIM + lane*2);
    ax[4] += bfbits_lo(v0); ay[4] += bfbits_hi(v0);
    ax[5] += bfbits_lo(v1); ay[5] += bfbits_hi(v1);
    i += 2;
  }
  if(i < s1){
    unsigned v0 = *(const unsigned*)(xb + (size_t)csr[i]*FDIM + lane*2);
    ax[6] += bfbits_lo(v0); ay[6] += bfbits_hi(v0);
  }
  float axs = ((ax[0]+ax[1])+(ax[2]+ax[3])) + ((ax[4]+ax[5])+(ax[6]+ax[7]));
  float ays = ((ay[0]+ay[1])+(ay[2]+ay[3])) + ((ay[4]+ay[5])+(ay[6]+ay[7]));
  unsigned o = (unsigned)bfb(axs) | ((unsigned)bfb(ays) << 16);
  *(unsigned*)(agg + (size_t)wid*FDIM + lane*2) = o;
}

// ---------------- weight prepack: Wc=[Wr;Wroot] -> bf16 MFMA fragments ----------------
// frag (kk,cb): holds Wc[k = kk*32 + (lane>>4)*8 + e][col = cb*16 + (lane&15)]
__global__ void wprep_kernel(const float* __restrict__ Wrel, const float* __restrict__ Wroot,
                             bf16_t* __restrict__ Bp){
  int gid = blockIdx.x*256 + threadIdx.x;
  if(gid >= NLAYERS*64*64) return;
  int lane = gid & 63;
  int fg   = (gid>>6) & 63;
  int l    = gid >> 12;
  int kk = fg >> 3, cb = fg & 7;
  int kbase = kk*32 + (lane>>4)*8;
  int col   = cb*16 + (lane&15);
  bf16_t tmp[8];
  #pragma unroll
  for(int e=0;e<8;e++){
    int k = kbase + e;
    float v = (k < FDIM) ? Wrel [l*FDIM*FDIM + k*FDIM + col]
                         : Wroot[l*FDIM*FDIM + (k-FDIM)*FDIM + col];
    tmp[e] = f2bf(v);
  }
  bf16_t* o = Bp + (long)gid*8;
  #pragma unroll
  for(int e=0;e<8;e++) o[e] = tmp[e];
}

// ---------------- fused GEMM: out = epi(agg@Wr + x@Wroot + b) ----------------
// Global-B (no LDS), 2 tiles (32 rows) per wave. B-fragments REGISTER
// DOUBLE-BUFFERED: kk+1's 8 frags prefetched while kk's MFMAs run, so L2
// latency hides under compute. __launch_bounds__(256,1) lifts the VGPR cap
// (~150 live regs) so the prefetch buffer doesn't spill.
__global__ __launch_bounds__(256, 1) void gemm_kernel(
    const bf16_t* __restrict__ Aagg, const bf16_t* __restrict__ Ain,
    const bf16_t* __restrict__ Bp, const float* __restrict__ bias,
    bf16_t* __restrict__ outB, float* __restrict__ outF,
    int relu, int resf, int npairs){
  int lane = threadIdx.x & 63;
  int gw   = (blockIdx.x*256 + threadIdx.x) >> 6;   // one 32-row pair per wave
  if(gw >= npairs) return;
  int r_lo = lane & 15;
  int kgrp = lane >> 4;
  long r0 = (long)gw*32;

  const bf16_t* pa0 = Aagg + (r0      + r_lo)*FDIM + kgrp*8;
  const bf16_t* pa1 = Aagg + (r0 + 16 + r_lo)*FDIM + kgrp*8;
  const bf16_t* pi0 = Ain  + (r0      + r_lo)*FDIM + kgrp*8;
  const bf16_t* pi1 = Ain  + (r0 + 16 + r_lo)*FDIM + kgrp*8;

  bf16x8 wcur[8], wnxt[8];
  #pragma unroll
  for(int cb=0;cb<8;cb++) wcur[cb] = *(const bf16x8*)(Bp + (cb*64 + lane)*8);

  f32x4 acc0[8] = {};
  f32x4 acc1[8] = {};
  #pragma unroll
  for(int kk=0;kk<8;kk++){
    bf16x8 a0 = (kk<4) ? *(const bf16x8*)(pa0 + kk*32) : *(const bf16x8*)(pi0 + (kk-4)*32);
    bf16x8 a1 = (kk<4) ? *(const bf16x8*)(pa1 + kk*32) : *(const bf16x8*)(pi1 + (kk-4)*32);
    if(kk < 7){
      #pragma unroll
      for(int cb=0;cb<8;cb++)
        wnxt[cb] = *(const bf16x8*)(Bp + ((((kk+1)<<3)|cb)*64 + lane)*8);
    }
    #pragma unroll
    for(int cb=0;cb<8;cb++){
      acc0[cb] = __builtin_amdgcn_mfma_f32_16x16x32_bf16(wcur[cb], a0, acc0[cb], 0, 0, 0);
      acc1[cb] = __builtin_amdgcn_mfma_f32_16x16x32_bf16(wcur[cb], a1, acc1[cb], 0, 0, 0);
    }
    if(kk < 7){
      #pragma unroll
      for(int cb=0;cb<8;cb++) wcur[cb] = wnxt[cb];
    }
  }
  // epilogue: two rows per lane: r0+r_lo and r0+16+r_lo; cols cb*16+kgrp*4..+3
  #pragma unroll
  for(int half=0; half<2; half++){
    long nrow = r0 + half*16 + r_lo;
    f32x4* acc = half ? acc1 : acc0;
    #pragma unroll
    for(int cb=0;cb<8;cb++){
      int col = cb*16 + kgrp*4;
      float4 bv = *(const float4*)(bias + col);
      float v0 = acc[cb][0] + bv.x;
      float v1 = acc[cb][1] + bv.y;
      float v2 = acc[cb][2] + bv.z;
      float v3 = acc[cb][3] + bv.w;
      if(relu){ v0=fmaxf(v0,0.f); v1=fmaxf(v1,0.f); v2=fmaxf(v2,0.f); v3=fmaxf(v3,0.f); }
      if(resf){
        ushort4 rv = *(const ushort4*)((const unsigned short*)Ain + nrow*FDIM + col);
        v0 += us2f(rv.x); v1 += us2f(rv.y); v2 += us2f(rv.z); v3 += us2f(rv.w);
      }
      if(outF){
        float4 o; o.x=v0; o.y=v1; o.z=v2; o.w=v3;
        *(float4*)(outF + nrow*FDIM + col) = o;
      } else {
        uint2 o;
        o.x = (unsigned)bfb(v0) | ((unsigned)bfb(v1) << 16);
        o.y = (unsigned)bfb(v2) | ((unsigned)bfb(v3) << 16);
        *(uint2*)((unsigned short*)outB + nrow*FDIM + col) = o;
      }
    }
  }
}

extern "C" void kernel_launch(void* const* d_in, const int* in_sizes, int n_in,
                              void* d_out, int out_size, void* d_ws, size_t ws_size,
                              hipStream_t stream){
  const float* x     = (const float*)d_in[0];
  const int*   ei    = (const int*)  d_in[1];
  const float* Wrel  = (const float*)d_in[2];
  const float* brel  = (const float*)d_in[3];
  const float* Wroot = (const float*)d_in[4];
  float* out = (float*)d_out;

  const int N = NNODES;
  const int E = in_sizes[1] / 2;
  const int* srcv = ei;
  const int* dstv = ei + E;

  char* w = (char*)d_ws;
  auto alloc = [&](size_t b)->char*{ char* p = w; w += (b + 255) & ~(size_t)255; return p; };
  unsigned short* xb  = (unsigned short*)alloc((size_t)N*FDIM*2);
  unsigned short* h_a = (unsigned short*)alloc((size_t)N*FDIM*2);
  unsigned short* h_b = (unsigned short*)alloc((size_t)N*FDIM*2);
  unsigned short* agg = (unsigned short*)alloc((size_t)N*FDIM*2);
  int*    deg       = (int*)   alloc((size_t)N*4);
  int*    cnt       = (int*)   alloc((size_t)N*4);
  int*    row_start = (int*)   alloc((size_t)(N+1)*4);
  int*    csr       = (int*)   alloc((size_t)E*4);
  bf16_t* Bp        = (bf16_t*)alloc((size_t)NLAYERS*4096*8*2);
  int*    sums      = (int*)   alloc(512);

  hipMemsetAsync(deg, 0, (size_t)N*4, stream);
  hipMemsetAsync(cnt, 0, (size_t)N*4, stream);

  int eb = (E + 255) / 256;
  int nchunks = (N + 1023) / 1024;
  deg_kernel <<<eb, 256, 0, stream>>>(dstv, deg, E);
  scan1_kernel<<<nchunks, 256, 0, stream>>>(deg, row_start, sums, N);
  scan2_kernel<<<1, 128, 0, stream>>>(sums, nchunks);
  scan3_kernel<<<(N + 1 + 255)/256, 256, 0, stream>>>(row_start, sums, N, E);
  fill_kernel<<<eb, 256, 0, stream>>>(srcv, dstv, row_start, cnt, csr, E);
  wprep_kernel<<<(NLAYERS*4096 + 255)/256, 256, 0, stream>>>(Wrel, Wroot, Bp);
  cvt_kernel  <<<(N*FDIM/8 + 255)/256, 256, 0, stream>>>(x, xb);

  const int npairs  = N / 32;                 // 3125 wave-pairs, exact
  const int gblocks = (npairs + 3) / 4;       // 782 blocks of 4 waves

  typedef unsigned short us;
  struct Lay { const us* in; us* o; int relu; int res; };
  Lay L[5] = {
    { xb,  h_a, 1, 0 },
    { h_a, h_b, 1, 1 },
    { h_b, h_a, 1, 1 },
    { h_a, h_b, 1, 1 },
    { h_b, 0,   0, 1 },
  };
  for(int l=0; l<NLAYERS; l++){
    gather_kernel<<<N/4, 256, 0, stream>>>(L[l].in, row_start, csr, agg, N);
    gemm_kernel  <<<gblocks, 256, 0, stream>>>((const bf16_t*)agg, (const bf16_t*)L[l].in,
                                               Bp + (size_t)l*4096*8,
                                               brel + l*FDIM,
                                               (bf16_t*)L[l].o, (l==4)? out : nullptr,
                                               L[l].relu, L[l].res, npairs);
  }
}

// Round 8
// 429.502 us; speedup vs baseline: 1.6618x; 1.0415x over previous
//
#include <hip/hip_runtime.h>

#define NNODES 100000
#define FDIM 128
#define NLAYERS 5

typedef __bf16 bf16_t;
typedef bf16_t bf16x8 __attribute__((ext_vector_type(8)));
typedef float  f32x4  __attribute__((ext_vector_type(4)));

__device__ __forceinline__ bf16_t f2bf(float f){ return (bf16_t)f; }
__device__ __forceinline__ float bfbits_lo(unsigned u){
  unsigned b = u << 16; return __builtin_bit_cast(float, b);
}
__device__ __forceinline__ float bfbits_hi(unsigned u){
  unsigned b = u & 0xffff0000u; return __builtin_bit_cast(float, b);
}
__device__ __forceinline__ unsigned short bfb(float f){
  bf16_t b = (bf16_t)f; return __builtin_bit_cast(unsigned short, b);
}
__device__ __forceinline__ float us2f(unsigned short u){
  unsigned b = ((unsigned)u) << 16; return __builtin_bit_cast(float, b);
}

// ---------------- CSR build ----------------
__global__ void deg_kernel(const int* __restrict__ dstv, int* __restrict__ deg, int E){
  int e = blockIdx.x*256 + threadIdx.x;
  if(e < E) atomicAdd(&deg[dstv[e]], 1);
}

__global__ void scan1_kernel(const int* __restrict__ deg, int* __restrict__ row_start,
                             int* __restrict__ sums, int n){
  __shared__ int sm[256];
  int t = threadIdx.x;
  int base = blockIdx.x*1024 + t*4;
  int v0=0,v1=0,v2=0,v3=0;
  if(base+3 < n){ int4 q = *(const int4*)(deg+base); v0=q.x; v1=q.y; v2=q.z; v3=q.w; }
  else {
    if(base   < n) v0 = deg[base];
    if(base+1 < n) v1 = deg[base+1];
    if(base+2 < n) v2 = deg[base+2];
    if(base+3 < n) v3 = deg[base+3];
  }
  int s = v0+v1+v2+v3;
  sm[t] = s;
  __syncthreads();
  for(int off=1; off<256; off<<=1){
    int y = (t>=off) ? sm[t-off] : 0;
    __syncthreads();
    sm[t] += y;
    __syncthreads();
  }
  int excl = sm[t] - s;
  if(base   < n) row_start[base]   = excl;
  if(base+1 < n) row_start[base+1] = excl+v0;
  if(base+2 < n) row_start[base+2] = excl+v0+v1;
  if(base+3 < n) row_start[base+3] = excl+v0+v1+v2;
  if(t == 255) sums[blockIdx.x] = sm[255];
}

__global__ void scan2_kernel(int* sums, int nc){
  __shared__ int sm[128];
  int t = threadIdx.x;
  int v = (t<nc) ? sums[t] : 0;
  sm[t] = v;
  __syncthreads();
  for(int off=1; off<128; off<<=1){
    int y = (t>=off) ? sm[t-off] : 0;
    __syncthreads();
    sm[t] += y;
    __syncthreads();
  }
  if(t<nc) sums[t] = sm[t] - v;
}

__global__ void scan3_kernel(int* row_start, const int* __restrict__ sums, int n, int E){
  int i = blockIdx.x*256 + threadIdx.x;
  if(i < n)       row_start[i] += sums[i>>10];
  else if(i == n) row_start[n]  = E;
}

__global__ void fill_kernel(const int* __restrict__ srcv, const int* __restrict__ dstv,
                            const int* __restrict__ row_start, int* __restrict__ cnt,
                            int* __restrict__ csr, int E){
  int e = blockIdx.x*256 + threadIdx.x;
  if(e < E){
    int d = dstv[e];
    int p = atomicAdd(&cnt[d], 1);
    csr[row_start[d] + p] = srcv[e];
  }
}

// ---------------- x fp32 -> bf16 pre-convert ----------------
__global__ __launch_bounds__(256) void cvt_kernel(const float* __restrict__ x,
                                                  unsigned short* __restrict__ xb){
  long i = ((long)blockIdx.x*256 + threadIdx.x)*8;
  float4 q0 = *(const float4*)(x+i);
  float4 q1 = *(const float4*)(x+i+4);
  unsigned short o[8];
  o[0]=bfb(q0.x); o[1]=bfb(q0.y); o[2]=bfb(q0.z); o[3]=bfb(q0.w);
  o[4]=bfb(q1.x); o[5]=bfb(q1.y); o[6]=bfb(q1.z); o[7]=bfb(q1.w);
  *(ulong2*)(xb+i) = *(ulong2*)o;
}

// ---------------- per-node gather, 8 loads in flight ----------------
__global__ __launch_bounds__(256) void gather_kernel(const unsigned short* __restrict__ xb,
                                                     const int* __restrict__ row_start,
                                                     const int* __restrict__ csr,
                                                     unsigned short* __restrict__ agg, int n){
  int wid  = (blockIdx.x*256 + threadIdx.x) >> 6;
  int lane = threadIdx.x & 63;
  if(wid >= n) return;
  int s0 = row_start[wid];
  int s1 = row_start[wid+1];
  float ax[8] = {}, ay[8] = {};
  int i = s0;
  for(; i+8 <= s1; i += 8){
    unsigned v[8];
    #pragma unroll
    for(int j=0;j<8;j++){
      int c = csr[i+j];
      v[j] = *(const unsigned*)(xb + (size_t)c*FDIM + lane*2);
    }
    #pragma unroll
    for(int j=0;j<8;j++){ ax[j] += bfbits_lo(v[j]); ay[j] += bfbits_hi(v[j]); }
  }
  if(i+4 <= s1){
    unsigned v[4];
    #pragma unroll
    for(int j=0;j<4;j++){
      int c = csr[i+j];
      v[j] = *(const unsigned*)(xb + (size_t)c*FDIM + lane*2);
    }
    #pragma unroll
    for(int j=0;j<4;j++){ ax[j] += bfbits_lo(v[j]); ay[j] += bfbits_hi(v[j]); }
    i += 4;
  }
  if(i+2 <= s1){
    unsigned v0 = *(const unsigned*)(xb + (size_t)csr[i]*FDIM + lane*2);
    unsigned v1 = *(const unsigned*)(xb + (size_t)csr[i+1]*FDIM + lane*2);
    ax[4] += bfbits_lo(v0); ay[4] += bfbits_hi(v0);
    ax[5] += bfbits_lo(v1); ay[5] += bfbits_hi(v1);
    i += 2;
  }
  if(i < s1){
    unsigned v0 = *(const unsigned*)(xb + (size_t)csr[i]*FDIM + lane*2);
    ax[6] += bfbits_lo(v0); ay[6] += bfbits_hi(v0);
  }
  float axs = ((ax[0]+ax[1])+(ax[2]+ax[3])) + ((ax[4]+ax[5])+(ax[6]+ax[7]));
  float ays = ((ay[0]+ay[1])+(ay[2]+ay[3])) + ((ay[4]+ay[5])+(ay[6]+ay[7]));
  unsigned o = (unsigned)bfb(axs) | ((unsigned)bfb(ays) << 16);
  *(unsigned*)(agg + (size_t)wid*FDIM + lane*2) = o;
}

// ---------------- weight prepack: Wc=[Wr;Wroot] -> bf16 MFMA fragments ----------------
// frag (kk,cb): holds Wc[k = kk*32 + (lane>>4)*8 + e][col = cb*16 + (lane&15)]
__global__ void wprep_kernel(const float* __restrict__ Wrel, const float* __restrict__ Wroot,
                             bf16_t* __restrict__ Bp){
  int gid = blockIdx.x*256 + threadIdx.x;
  if(gid >= NLAYERS*64*64) return;
  int lane = gid & 63;
  int fg   = (gid>>6) & 63;
  int l    = gid >> 12;
  int kk = fg >> 3, cb = fg & 7;
  int kbase = kk*32 + (lane>>4)*8;
  int col   = cb*16 + (lane&15);
  bf16_t tmp[8];
  #pragma unroll
  for(int e=0;e<8;e++){
    int k = kbase + e;
    float v = (k < FDIM) ? Wrel [l*FDIM*FDIM + k*FDIM + col]
                         : Wroot[l*FDIM*FDIM + (k-FDIM)*FDIM + col];
    tmp[e] = f2bf(v);
  }
  bf16_t* o = Bp + (long)gid*8;
  #pragma unroll
  for(int e=0;e<8;e++) o[e] = tmp[e];
}

// ---------------- fused GEMM: out = epi(agg@Wr + x@Wroot + b) ----------------
// Max-TLP variant: ONE 16-row tile per wave, exact grid (6250 waves needed,
// 24.4 waves/CU). Live set ~56 VGPR (<=64 -> 8 waves/SIMD cap) so latency of
// the 64 just-in-time B-fragment L2 loads is hidden by thread-level
// parallelism, not in-wave pipelining (which the compiler defeats anyway).
__global__ __launch_bounds__(256) void gemm_kernel(
    const bf16_t* __restrict__ Aagg, const bf16_t* __restrict__ Ain,
    const bf16_t* __restrict__ Bp, const float* __restrict__ bias,
    bf16_t* __restrict__ outB, float* __restrict__ outF,
    int relu, int resf, int ntiles){
  int lane = threadIdx.x & 63;
  int t    = (blockIdx.x*256 + threadIdx.x) >> 6;   // one 16-row tile per wave
  if(t >= ntiles) return;
  int r_lo = lane & 15;
  int kgrp = lane >> 4;
  long r0 = (long)t*16;

  const bf16_t* pa = Aagg + (r0 + r_lo)*FDIM + kgrp*8;
  const bf16_t* pi = Ain  + (r0 + r_lo)*FDIM + kgrp*8;

  f32x4 acc[8] = {};
  #pragma unroll
  for(int kk=0;kk<8;kk++){
    bf16x8 a = (kk<4) ? *(const bf16x8*)(pa + kk*32) : *(const bf16x8*)(pi + (kk-4)*32);
    #pragma unroll
    for(int cb=0;cb<8;cb++){
      bf16x8 wfr = *(const bf16x8*)(Bp + (((kk<<3)|cb)*64 + lane)*8);
      acc[cb] = __builtin_amdgcn_mfma_f32_16x16x32_bf16(wfr, a, acc[cb], 0, 0, 0);
    }
  }
  // epilogue: lane owns node row r0+r_lo, cols cb*16 + kgrp*4 .. +3
  long nrow = r0 + r_lo;
  #pragma unroll
  for(int cb=0;cb<8;cb++){
    int col = cb*16 + kgrp*4;
    float4 bv = *(const float4*)(bias + col);
    float v0 = acc[cb][0] + bv.x;
    float v1 = acc[cb][1] + bv.y;
    float v2 = acc[cb][2] + bv.z;
    float v3 = acc[cb][3] + bv.w;
    if(relu){ v0=fmaxf(v0,0.f); v1=fmaxf(v1,0.f); v2=fmaxf(v2,0.f); v3=fmaxf(v3,0.f); }
    if(resf){
      ushort4 rv = *(const ushort4*)((const unsigned short*)Ain + nrow*FDIM + col);
      v0 += us2f(rv.x); v1 += us2f(rv.y); v2 += us2f(rv.z); v3 += us2f(rv.w);
    }
    if(outF){
      float4 o; o.x=v0; o.y=v1; o.z=v2; o.w=v3;
      *(float4*)(outF + nrow*FDIM + col) = o;
    } else {
      uint2 o;
      o.x = (unsigned)bfb(v0) | ((unsigned)bfb(v1) << 16);
      o.y = (unsigned)bfb(v2) | ((unsigned)bfb(v3) << 16);
      *(uint2*)((unsigned short*)outB + nrow*FDIM + col) = o;
    }
  }
}

extern "C" void kernel_launch(void* const* d_in, const int* in_sizes, int n_in,
                              void* d_out, int out_size, void* d_ws, size_t ws_size,
                              hipStream_t stream){
  const float* x     = (const float*)d_in[0];
  const int*   ei    = (const int*)  d_in[1];
  const float* Wrel  = (const float*)d_in[2];
  const float* brel  = (const float*)d_in[3];
  const float* Wroot = (const float*)d_in[4];
  float* out = (float*)d_out;

  const int N = NNODES;
  const int E = in_sizes[1] / 2;
  const int* srcv = ei;
  const int* dstv = ei + E;

  char* w = (char*)d_ws;
  auto alloc = [&](size_t b)->char*{ char* p = w; w += (b + 255) & ~(size_t)255; return p; };
  unsigned short* xb  = (unsigned short*)alloc((size_t)N*FDIM*2);
  unsigned short* h_a = (unsigned short*)alloc((size_t)N*FDIM*2);
  unsigned short* h_b = (unsigned short*)alloc((size_t)N*FDIM*2);
  unsigned short* agg = (unsigned short*)alloc((size_t)N*FDIM*2);
  int*    deg       = (int*)   alloc((size_t)N*4);
  int*    cnt       = (int*)   alloc((size_t)N*4);
  int*    row_start = (int*)   alloc((size_t)(N+1)*4);
  int*    csr       = (int*)   alloc((size_t)E*4);
  bf16_t* Bp        = (bf16_t*)alloc((size_t)NLAYERS*4096*8*2);
  int*    sums      = (int*)   alloc(512);

  hipMemsetAsync(deg, 0, (size_t)N*4, stream);
  hipMemsetAsync(cnt, 0, (size_t)N*4, stream);

  int eb = (E + 255) / 256;
  int nchunks = (N + 1023) / 1024;
  deg_kernel <<<eb, 256, 0, stream>>>(dstv, deg, E);
  scan1_kernel<<<nchunks, 256, 0, stream>>>(deg, row_start, sums, N);
  scan2_kernel<<<1, 128, 0, stream>>>(sums, nchunks);
  scan3_kernel<<<(N + 1 + 255)/256, 256, 0, stream>>>(row_start, sums, N, E);
  fill_kernel<<<eb, 256, 0, stream>>>(srcv, dstv, row_start, cnt, csr, E);
  wprep_kernel<<<(NLAYERS*4096 + 255)/256, 256, 0, stream>>>(Wrel, Wroot, Bp);
  cvt_kernel  <<<(N*FDIM/8 + 255)/256, 256, 0, stream>>>(x, xb);

  const int ntiles  = N / 16;                 // 6250 tiles, 1 per wave
  const int gblocks = (ntiles + 3) / 4;       // 1563 blocks of 4 waves

  typedef unsigned short us;
  struct Lay { const us* in; us* o; int relu; int res; };
  Lay L[5] = {
    { xb,  h_a, 1, 0 },
    { h_a, h_b, 1, 1 },
    { h_b, h_a, 1, 1 },
    { h_a, h_b, 1, 1 },
    { h_b, 0,   0, 1 },
  };
  for(int l=0; l<NLAYERS; l++){
    gather_kernel<<<N/4, 256, 0, stream>>>(L[l].in, row_start, csr, agg, N);
    gemm_kernel  <<<gblocks, 256, 0, stream>>>((const bf16_t*)agg, (const bf16_t*)L[l].in,
                                               Bp + (size_t)l*4096*8,
                                               brel + l*FDIM,
                                               (bf16_t*)L[l].o, (l==4)? out : nullptr,
                                               L[l].relu, L[l].res, ntiles);
  }
}